// Round 9
// baseline (341.862 us; speedup 1.0000x reference)
//
#include <hip/hip_runtime.h>
#include <hip/hip_bf16.h>

typedef __bf16 v8bf __attribute__((ext_vector_type(8)));
typedef __bf16 v4bf __attribute__((ext_vector_type(4)));
typedef float  f32x4 __attribute__((ext_vector_type(4)));
typedef unsigned int u32;

#define NTOK 1024
#define HDIM 1024
#define FDIM 3584
#define NEXP 8
#define NPAIR 2048
#define MAXT 32
#define KSPLIT2 2
#define KPER2 (FDIM / KSPLIT2)   // 1792

// workspace layout (bytes)
#define OFF_COUNTS   0
#define OFF_OFFSETS  64
#define OFF_NT1      128
#define OFF_T1E      192
#define OFF_T1M      320
#define OFF_TOKIDX   2048
#define OFF_TOKWT    (2048 + 4*NPAIR)
#define OFF_PAIRTOK  (OFF_TOKWT + 4*NPAIR)
#define OFF_PAIRWT   (OFF_PAIRTOK + 4*NPAIR)
#define OFF_SLOTOF   (OFF_PAIRWT + 4*NPAIR)
#define OFF_XB       65536                          // bf16 [1024][1024] = 2 MB
#define OFF_ACT      (OFF_XB + 2ull*NTOK*HDIM)      // bf16 [2048][3584]
#define OFF_Y        (OFF_ACT + 2ull*NPAIR*FDIM)    // f32  [2][2048][1024]
#define YSTRIDE      ((size_t)NPAIR * HDIM)

static __device__ inline v4bf cvt4(float4 f) {
    v4bf r;
    r[0] = (__bf16)f.x; r[1] = (__bf16)f.y; r[2] = (__bf16)f.z; r[3] = (__bf16)f.w;
    return r;
}

static __device__ inline v8bf pack8(f32x4 lo, f32x4 hi) {
    v8bf r;
    r[0] = (__bf16)lo[0]; r[1] = (__bf16)lo[1]; r[2] = (__bf16)lo[2]; r[3] = (__bf16)lo[3];
    r[4] = (__bf16)hi[0]; r[5] = (__bf16)hi[1]; r[6] = (__bf16)hi[2]; r[7] = (__bf16)hi[3];
    return r;
}

#define FENCE() asm volatile("" ::: "memory")
#define WAITVM0() asm volatile("s_waitcnt vmcnt(0)" ::: "memory")
#define WAITLGKM0() asm volatile("s_waitcnt lgkmcnt(0)" ::: "memory")

#define DMA16(SRC, DST) \
    __builtin_amdgcn_global_load_lds((const __attribute__((address_space(1))) u32*)(SRC), \
                                     (__attribute__((address_space(3))) u32*)(DST), 16, 0, 0)

// ---------------- x -> bf16 ----------------
__global__ __launch_bounds__(256) void moe_cvtx(const float* __restrict__ x,
                                                __bf16* __restrict__ xb)
{
    const size_t i = ((size_t)blockIdx.x * 256 + threadIdx.x) * 4;
    float4 v = *(const float4*)(x + i);
    *(v4bf*)(xb + i) = cvt4(v);
}

// ---------------- router ----------------
__global__ __launch_bounds__(256) void moe_router(
    const float* __restrict__ x, const float* __restrict__ gw,
    float* __restrict__ logits, int* __restrict__ counts,
    int* __restrict__ tok_idx, float* __restrict__ tok_wt)
{
    const int lane = threadIdx.x & 63;
    const int wv = threadIdx.x >> 6;
    const int t = blockIdx.x * 4 + wv;
    const float* xr = x + (size_t)t * HDIM;

    float acc[NEXP];
#pragma unroll
    for (int e = 0; e < NEXP; ++e) acc[e] = 0.f;
#pragma unroll
    for (int j = 0; j < 4; ++j) {
        int h = lane * 4 + j * 256;
        float4 xv = *(const float4*)(xr + h);
#pragma unroll
        for (int e = 0; e < NEXP; ++e) {
            float4 g = *(const float4*)(gw + e * HDIM + h);
            acc[e] += xv.x * g.x + xv.y * g.y + xv.z * g.z + xv.w * g.w;
        }
    }
#pragma unroll
    for (int e = 0; e < NEXP; ++e) {
#pragma unroll
        for (int s = 32; s > 0; s >>= 1) acc[e] += __shfl_xor(acc[e], s);
    }
    if (lane == 0) {
#pragma unroll
        for (int e = 0; e < NEXP; ++e) logits[t * NEXP + e] = acc[e];
        int i0 = 0;
#pragma unroll
        for (int e = 1; e < NEXP; ++e) if (acc[e] > acc[i0]) i0 = e;
        int i1 = (i0 == 0) ? 1 : 0;
#pragma unroll
        for (int e = 0; e < NEXP; ++e) if (e != i0 && acc[e] > acc[i1]) i1 = e;
        float w0 = 1.f / (1.f + expf(acc[i1] - acc[i0]));
        float w1 = 1.f - w0;
        tok_idx[2 * t] = i0; tok_idx[2 * t + 1] = i1;
        tok_wt[2 * t] = w0;  tok_wt[2 * t + 1] = w1;
        atomicAdd(&counts[i0], 1);
        atomicAdd(&counts[i1], 1);
    }
}

// ---------------- scatter + tile list (BM=128) ----------------
__global__ void moe_scatter(const int* __restrict__ counts, const int* __restrict__ tok_idx,
                            const float* __restrict__ tok_wt, int* __restrict__ offsets,
                            int* __restrict__ pair_token, float* __restrict__ pair_wt,
                            int* __restrict__ slot_of,
                            int* __restrict__ t1e, int* __restrict__ t1m, int* __restrict__ nt1)
{
    __shared__ int cur[NEXP];
    const int tid = threadIdx.x;
    if (tid == 0) {
        int run = 0, n1 = 0;
        for (int e = 0; e < NEXP; ++e) {
            offsets[e] = run; cur[e] = run;
            for (int m0 = 0; m0 < counts[e]; m0 += 128) { t1e[n1] = e; t1m[n1] = m0; ++n1; }
            run += counts[e];
        }
        *nt1 = n1;
    }
    __syncthreads();
    for (int p = tid; p < 2 * NTOK; p += blockDim.x) {
        int e = tok_idx[p];
        int s = atomicAdd(&cur[e], 1);
        pair_token[s] = p >> 1;
        pair_wt[s] = tok_wt[p];
        slot_of[p] = s;
    }
}

// ---------------- GEMM1: act = silu(X@w1^T)*(X@w3^T) ----------------
// BM=128 BN=64 BK=64. A: bf16 via DMA16 into double-buffered swizzled LDS.
// B (w1,w3 fp32): per-lane direct global loads -> pack8 -> MFMA (no LDS, no barrier coupling).
__global__ __launch_bounds__(256, 2) void moe_gemm1(
    const __bf16* __restrict__ xb, const float* __restrict__ w1g,
    const float* __restrict__ w3g, const int* __restrict__ counts,
    const int* __restrict__ offsets, const int* __restrict__ pair_token,
    const int* __restrict__ t1e, const int* __restrict__ t1m,
    const int* __restrict__ nt1,
    __bf16* __restrict__ act)
{
    const int ty = blockIdx.y;
    if (ty >= *nt1) return;
    const int e = t1e[ty];
    const int m0 = t1m[ty];
    const int Me = counts[e];
    const int rows = min(128, Me - m0);
    const int slot0 = offsets[e] + m0;
    const int n0 = blockIdx.x * 64;

    __shared__ __align__(16) __bf16 As[2][128 * 64];   // 16 KB x2

    const int tid = threadIdx.x;
    const int lane = tid & 63;
    const int wv = tid >> 6;
    const int ln4 = lane >> 4;
    const int lr = lane & 15;
    const int wm = (wv >> 1) * 64;
    const int wn = (wv & 1) * 32;

    f32x4 acc1[4][2], acc3[4][2];
#pragma unroll
    for (int i = 0; i < 4; ++i)
#pragma unroll
        for (int j = 0; j < 2; ++j) {
            acc1[i][j] = (f32x4){0.f, 0.f, 0.f, 0.f};
            acc3[i][j] = (f32x4){0.f, 0.f, 0.f, 0.f};
        }

    // A: 1024 chunks of 16B per buf (128 rows x 8 chunks); 4 per thread.
    // Source pre-swizzle sj = (c&7)^(r&7); LDS dest linear (verified conflict-free, R7).
    const char* asrc[4];
#pragma unroll
    for (int i = 0; i < 4; ++i) {
        int c = i * 256 + tid;
        int r = c >> 3;
        int rr = (r < rows) ? r : 0;
        int sj = (c & 7) ^ (r & 7);
        asrc[i] = (const char*)(xb + (size_t)pair_token[slot0 + rr] * HDIM) + sj * 16;
    }

    // B row pointers: lane covers row n = n0+wn+ni*16+lr, k-slice starts at ln4*8
    const float* b1p[2];
    const float* b3p[2];
#pragma unroll
    for (int ni = 0; ni < 2; ++ni) {
        size_t row = (size_t)e * FDIM + n0 + wn + ni * 16 + lr;
        b1p[ni] = w1g + row * HDIM + ln4 * 8;
        b3p[ni] = w3g + row * HDIM + ln4 * 8;
    }

    // swizzled A read byte-offsets
    int aoff[4][2];
#pragma unroll
    for (int mi = 0; mi < 4; ++mi) {
#pragma unroll
        for (int kh = 0; kh < 2; ++kh) {
            int row = wm + mi * 16 + lr;
            aoff[mi][kh] = row * 128 + ((kh * 64 + ln4 * 16) ^ ((row & 7) << 4));
        }
    }

#define DMA_A1(BUF, K0) do { _Pragma("unroll") \
    for (int i = 0; i < 4; ++i) \
        DMA16(asrc[i] + (size_t)(K0) * 2, (char*)&As[BUF][0] + (i * 256 + wv * 64) * 16); \
    } while (0)

    DMA_A1(0, 0);
    WAITVM0();
    FENCE(); __builtin_amdgcn_s_barrier(); FENCE();

    int buf = 0;
    for (int ks = 0; ks < HDIM / 64; ++ks) {
        if (ks + 1 < HDIM / 64) DMA_A1(buf ^ 1, (ks + 1) * 64);   // in flight during compute
#pragma unroll
        for (int kh = 0; kh < 2; ++kh) {
            const int k0 = ks * 64 + kh * 32;
            v8bf b1f[2], b3f[2];
#pragma unroll
            for (int ni = 0; ni < 2; ++ni) {
                f32x4 lo1 = *(const f32x4*)(b1p[ni] + k0);
                f32x4 hi1 = *(const f32x4*)(b1p[ni] + k0 + 4);
                f32x4 lo3 = *(const f32x4*)(b3p[ni] + k0);
                f32x4 hi3 = *(const f32x4*)(b3p[ni] + k0 + 4);
                b1f[ni] = pack8(lo1, hi1);
                b3f[ni] = pack8(lo3, hi3);
            }
            v8bf af[4];
#pragma unroll
            for (int mi = 0; mi < 4; ++mi)
                af[mi] = *(const v8bf*)((const char*)&As[buf][0] + aoff[mi][kh]);
#pragma unroll
            for (int mi = 0; mi < 4; ++mi) {
#pragma unroll
                for (int ni = 0; ni < 2; ++ni) {
                    acc1[mi][ni] = __builtin_amdgcn_mfma_f32_16x16x32_bf16(af[mi], b1f[ni], acc1[mi][ni], 0, 0, 0);
                    acc3[mi][ni] = __builtin_amdgcn_mfma_f32_16x16x32_bf16(af[mi], b3f[ni], acc3[mi][ni], 0, 0, 0);
                }
            }
        }
        if (ks + 1 < HDIM / 64) {
            WAITVM0();          // next-buf A landed (issued one full compute phase ago)
            WAITLGKM0();
            FENCE(); __builtin_amdgcn_s_barrier(); FENCE();
            buf ^= 1;
        }
    }
#undef DMA_A1

    const int rj = ln4 * 4;
#pragma unroll
    for (int mi = 0; mi < 4; ++mi) {
#pragma unroll
        for (int j = 0; j < 4; ++j) {
            int rm = wm + mi * 16 + rj + j;
            if (rm < rows) {
                size_t rowoff = (size_t)(slot0 + rm) * FDIM + n0 + wn;
#pragma unroll
                for (int ni = 0; ni < 2; ++ni) {
                    float h1 = acc1[mi][ni][j];
                    float h3 = acc3[mi][ni][j];
                    float sv = (h1 / (1.f + __expf(-h1))) * h3;
                    act[rowoff + ni * 16 + lr] = (__bf16)sv;
                }
            }
        }
    }
}

// ---------------- GEMM2: y_part = act @ w2^T; BM=128 BN=64 BK=64, split-K x2 ----------------
__global__ __launch_bounds__(256, 2) void moe_gemm2(
    const __bf16* __restrict__ act, const float* __restrict__ w2g,
    const int* __restrict__ counts, const int* __restrict__ offsets,
    const int* __restrict__ t1e, const int* __restrict__ t1m,
    const int* __restrict__ nt1,
    float* __restrict__ y)
{
    const int ty = blockIdx.y;
    if (ty >= *nt1) return;
    const int e = t1e[ty];
    const int m0 = t1m[ty];
    const int Me = counts[e];
    const int rows = min(128, Me - m0);
    const int slot0 = offsets[e] + m0;
    const int n0 = blockIdx.x * 64;
    const int kz = blockIdx.z;
    float* yout = y + (size_t)kz * YSTRIDE;
    const size_t kbase = (size_t)kz * KPER2;

    __shared__ __align__(16) __bf16 As[2][128 * 64];

    const int tid = threadIdx.x;
    const int lane = tid & 63;
    const int wv = tid >> 6;
    const int ln4 = lane >> 4;
    const int lr = lane & 15;
    const int wm = (wv >> 1) * 64;
    const int wn = (wv & 1) * 32;

    f32x4 acc[4][2];
#pragma unroll
    for (int i = 0; i < 4; ++i)
#pragma unroll
        for (int j = 0; j < 2; ++j) acc[i][j] = (f32x4){0.f, 0.f, 0.f, 0.f};

    const char* asrc[4];
#pragma unroll
    for (int i = 0; i < 4; ++i) {
        int c = i * 256 + tid;
        int r = c >> 3;
        int rr = (r < rows) ? r : 0;
        int sj = (c & 7) ^ (r & 7);
        asrc[i] = (const char*)(act + (size_t)(slot0 + rr) * FDIM + kbase) + sj * 16;
    }

    const float* bp[2];
#pragma unroll
    for (int ni = 0; ni < 2; ++ni) {
        size_t row = (size_t)e * HDIM + n0 + wn + ni * 16 + lr;
        bp[ni] = w2g + row * FDIM + kbase + ln4 * 8;
    }

    int aoff[4][2];
#pragma unroll
    for (int mi = 0; mi < 4; ++mi) {
#pragma unroll
        for (int kh = 0; kh < 2; ++kh) {
            int row = wm + mi * 16 + lr;
            aoff[mi][kh] = row * 128 + ((kh * 64 + ln4 * 16) ^ ((row & 7) << 4));
        }
    }

#define DMA_A2(BUF, K0) do { _Pragma("unroll") \
    for (int i = 0; i < 4; ++i) \
        DMA16(asrc[i] + (size_t)(K0) * 2, (char*)&As[BUF][0] + (i * 256 + wv * 64) * 16); \
    } while (0)

    DMA_A2(0, 0);
    WAITVM0();
    FENCE(); __builtin_amdgcn_s_barrier(); FENCE();

    int buf = 0;
    for (int ks = 0; ks < KPER2 / 64; ++ks) {
        if (ks + 1 < KPER2 / 64) DMA_A2(buf ^ 1, (ks + 1) * 64);
#pragma unroll
        for (int kh = 0; kh < 2; ++kh) {
            const int k0 = ks * 64 + kh * 32;
            v8bf bf[2];
#pragma unroll
            for (int ni = 0; ni < 2; ++ni) {
                f32x4 lo = *(const f32x4*)(bp[ni] + k0);
                f32x4 hi = *(const f32x4*)(bp[ni] + k0 + 4);
                bf[ni] = pack8(lo, hi);
            }
            v8bf af[4];
#pragma unroll
            for (int mi = 0; mi < 4; ++mi)
                af[mi] = *(const v8bf*)((const char*)&As[buf][0] + aoff[mi][kh]);
#pragma unroll
            for (int mi = 0; mi < 4; ++mi) {
#pragma unroll
                for (int ni = 0; ni < 2; ++ni)
                    acc[mi][ni] = __builtin_amdgcn_mfma_f32_16x16x32_bf16(af[mi], bf[ni], acc[mi][ni], 0, 0, 0);
            }
        }
        if (ks + 1 < KPER2 / 64) {
            WAITVM0();
            WAITLGKM0();
            FENCE(); __builtin_amdgcn_s_barrier(); FENCE();
            buf ^= 1;
        }
    }
#undef DMA_A2

    const int rj = ln4 * 4;
#pragma unroll
    for (int mi = 0; mi < 4; ++mi) {
#pragma unroll
        for (int j = 0; j < 4; ++j) {
            int rm = wm + mi * 16 + rj + j;
            if (rm < rows) {
                size_t rowoff = (size_t)(slot0 + rm) * HDIM + n0 + wn;
#pragma unroll
                for (int ni = 0; ni < 2; ++ni)
                    yout[rowoff + ni * 16 + lr] = acc[mi][ni][j];
            }
        }
    }
}

// ---------------- combine: out[t] = sum_kz( w0*y[s0] + w1*y[s1] ) ----------------
__global__ __launch_bounds__(256) void moe_combine(
    const float* __restrict__ y, const int* __restrict__ slot_of,
    const float* __restrict__ pair_wt, float* __restrict__ out)
{
    const int t = blockIdx.x;
    const int tid = threadIdx.x;
    const int s0 = slot_of[2 * t];
    const int s1 = slot_of[2 * t + 1];
    const float w0 = pair_wt[s0];
    const float w1 = pair_wt[s1];
    float4 a = {0.f, 0.f, 0.f, 0.f}, b = {0.f, 0.f, 0.f, 0.f};
#pragma unroll
    for (int k = 0; k < KSPLIT2; ++k) {
        const float4 ak = *(const float4*)(y + k * YSTRIDE + (size_t)s0 * HDIM + tid * 4);
        const float4 bk = *(const float4*)(y + k * YSTRIDE + (size_t)s1 * HDIM + tid * 4);
        a.x += ak.x; a.y += ak.y; a.z += ak.z; a.w += ak.w;
        b.x += bk.x; b.y += bk.y; b.z += bk.z; b.w += bk.w;
    }
    float4 o;
    o.x = w0 * a.x + w1 * b.x;
    o.y = w0 * a.y + w1 * b.y;
    o.z = w0 * a.z + w1 * b.z;
    o.w = w0 * a.w + w1 * b.w;
    *(float4*)(out + (size_t)t * HDIM + tid * 4) = o;
}

extern "C" void kernel_launch(void* const* d_in, const int* in_sizes, int n_in,
                              void* d_out, int out_size, void* d_ws, size_t ws_size,
                              hipStream_t stream) {
    const float* x   = (const float*)d_in[0];
    const float* gw  = (const float*)d_in[1];
    const float* w1  = (const float*)d_in[2];
    const float* w2  = (const float*)d_in[3];
    const float* w3  = (const float*)d_in[4];

    float* out    = (float*)d_out;
    float* logits = out + (size_t)NTOK * HDIM;

    char* ws = (char*)d_ws;
    int*    counts     = (int*)(ws + OFF_COUNTS);
    int*    offsets    = (int*)(ws + OFF_OFFSETS);
    int*    nt1        = (int*)(ws + OFF_NT1);
    int*    t1e        = (int*)(ws + OFF_T1E);
    int*    t1m        = (int*)(ws + OFF_T1M);
    int*    tok_idx    = (int*)(ws + OFF_TOKIDX);
    float*  tok_wt     = (float*)(ws + OFF_TOKWT);
    int*    pair_token = (int*)(ws + OFF_PAIRTOK);
    float*  pair_wt    = (float*)(ws + OFF_PAIRWT);
    int*    slot_of    = (int*)(ws + OFF_SLOTOF);
    __bf16* xb         = (__bf16*)(ws + OFF_XB);
    __bf16* act        = (__bf16*)(ws + OFF_ACT);
    float*  yb         = (float*)(ws + OFF_Y);

    hipMemsetAsync(counts, 0, 64, stream);

    moe_cvtx<<<dim3(NTOK * HDIM / 1024), dim3(256), 0, stream>>>(x, xb);
    moe_router<<<dim3(NTOK / 4), dim3(256), 0, stream>>>(x, gw, logits, counts, tok_idx, tok_wt);
    moe_scatter<<<dim3(1), dim3(256), 0, stream>>>(counts, tok_idx, tok_wt, offsets,
                                                   pair_token, pair_wt, slot_of,
                                                   t1e, t1m, nt1);
    moe_gemm1<<<dim3(FDIM / 64, MAXT), dim3(256), 0, stream>>>(
        xb, w1, w3, counts, offsets, pair_token, t1e, t1m, nt1, act);
    moe_gemm2<<<dim3(HDIM / 64, MAXT, KSPLIT2), dim3(256), 0, stream>>>(
        act, w2, counts, offsets, t1e, t1m, nt1, yb);
    moe_combine<<<dim3(NTOK), dim3(256), 0, stream>>>(yb, slot_of, pair_wt, out);
}

// Round 10
// 238.314 us; speedup vs baseline: 1.4345x; 1.4345x over previous
//
#include <hip/hip_runtime.h>
#include <hip/hip_bf16.h>

typedef __bf16 v8bf __attribute__((ext_vector_type(8)));
typedef __bf16 v4bf __attribute__((ext_vector_type(4)));
typedef float  f32x4 __attribute__((ext_vector_type(4)));
typedef unsigned int u32;

#define NTOK 1024
#define HDIM 1024
#define FDIM 3584
#define NEXP 8
#define NPAIR 2048
#define MAXT 16          // BM=256 tiles
#define KSPLIT2 4
#define KPER2 (FDIM / KSPLIT2)   // 896

// workspace layout (bytes)
#define OFF_COUNTS   0
#define OFF_OFFSETS  64
#define OFF_NT1      128
#define OFF_T1E      192
#define OFF_T1M      320
#define OFF_TOKIDX   2048
#define OFF_TOKWT    (2048 + 4*NPAIR)
#define OFF_PAIRTOK  (OFF_TOKWT + 4*NPAIR)
#define OFF_PAIRWT   (OFF_PAIRTOK + 4*NPAIR)
#define OFF_SLOTOF   (OFF_PAIRWT + 4*NPAIR)
#define OFF_XB       65536                          // bf16 [1024][1024] = 2 MB
#define OFF_ACT      (OFF_XB + 2ull*NTOK*HDIM)      // bf16 [2048][3584]
#define OFF_Y        (OFF_ACT + 2ull*NPAIR*FDIM)    // f32  [4][2048][1024]
#define YSTRIDE      ((size_t)NPAIR * HDIM)

static __device__ inline v4bf cvt4(float4 f) {
    v4bf r;
    r[0] = (__bf16)f.x; r[1] = (__bf16)f.y; r[2] = (__bf16)f.z; r[3] = (__bf16)f.w;
    return r;
}

static __device__ inline v8bf pack8(f32x4 lo, f32x4 hi) {
    v8bf r;
    r[0] = (__bf16)lo[0]; r[1] = (__bf16)lo[1]; r[2] = (__bf16)lo[2]; r[3] = (__bf16)lo[3];
    r[4] = (__bf16)hi[0]; r[5] = (__bf16)hi[1]; r[6] = (__bf16)hi[2]; r[7] = (__bf16)hi[3];
    return r;
}

#define FENCE() asm volatile("" ::: "memory")
#define BARRIER() do { FENCE(); __builtin_amdgcn_s_barrier(); FENCE(); } while (0)
#define WAITVM0() asm volatile("s_waitcnt vmcnt(0)" ::: "memory")
#define WAITLGKM0() asm volatile("s_waitcnt lgkmcnt(0)" ::: "memory")

#define DMA16(SRC, DST) \
    __builtin_amdgcn_global_load_lds((const __attribute__((address_space(1))) u32*)(SRC), \
                                     (__attribute__((address_space(3))) u32*)(DST), 16, 0, 0)

// ---------------- x -> bf16 ----------------
__global__ __launch_bounds__(256) void moe_cvtx(const float* __restrict__ x,
                                                __bf16* __restrict__ xb)
{
    const size_t i = ((size_t)blockIdx.x * 256 + threadIdx.x) * 4;
    float4 v = *(const float4*)(x + i);
    *(v4bf*)(xb + i) = cvt4(v);
}

// ---------------- router ----------------
__global__ __launch_bounds__(256) void moe_router(
    const float* __restrict__ x, const float* __restrict__ gw,
    float* __restrict__ logits, int* __restrict__ counts,
    int* __restrict__ tok_idx, float* __restrict__ tok_wt)
{
    const int lane = threadIdx.x & 63;
    const int wv = threadIdx.x >> 6;
    const int t = blockIdx.x * 4 + wv;
    const float* xr = x + (size_t)t * HDIM;

    float acc[NEXP];
#pragma unroll
    for (int e = 0; e < NEXP; ++e) acc[e] = 0.f;
#pragma unroll
    for (int j = 0; j < 4; ++j) {
        int h = lane * 4 + j * 256;
        float4 xv = *(const float4*)(xr + h);
#pragma unroll
        for (int e = 0; e < NEXP; ++e) {
            float4 g = *(const float4*)(gw + e * HDIM + h);
            acc[e] += xv.x * g.x + xv.y * g.y + xv.z * g.z + xv.w * g.w;
        }
    }
#pragma unroll
    for (int e = 0; e < NEXP; ++e) {
#pragma unroll
        for (int s = 32; s > 0; s >>= 1) acc[e] += __shfl_xor(acc[e], s);
    }
    if (lane == 0) {
#pragma unroll
        for (int e = 0; e < NEXP; ++e) logits[t * NEXP + e] = acc[e];
        int i0 = 0;
#pragma unroll
        for (int e = 1; e < NEXP; ++e) if (acc[e] > acc[i0]) i0 = e;
        int i1 = (i0 == 0) ? 1 : 0;
#pragma unroll
        for (int e = 0; e < NEXP; ++e) if (e != i0 && acc[e] > acc[i1]) i1 = e;
        float w0 = 1.f / (1.f + expf(acc[i1] - acc[i0]));
        float w1 = 1.f - w0;
        tok_idx[2 * t] = i0; tok_idx[2 * t + 1] = i1;
        tok_wt[2 * t] = w0;  tok_wt[2 * t + 1] = w1;
        atomicAdd(&counts[i0], 1);
        atomicAdd(&counts[i1], 1);
    }
}

// ---------------- scatter + tile list (BM=256) ----------------
__global__ void moe_scatter(const int* __restrict__ counts, const int* __restrict__ tok_idx,
                            const float* __restrict__ tok_wt, int* __restrict__ offsets,
                            int* __restrict__ pair_token, float* __restrict__ pair_wt,
                            int* __restrict__ slot_of,
                            int* __restrict__ t1e, int* __restrict__ t1m, int* __restrict__ nt1)
{
    __shared__ int cur[NEXP];
    const int tid = threadIdx.x;
    if (tid == 0) {
        int run = 0, n1 = 0;
        for (int e = 0; e < NEXP; ++e) {
            offsets[e] = run; cur[e] = run;
            for (int m0 = 0; m0 < counts[e]; m0 += 256) { t1e[n1] = e; t1m[n1] = m0; ++n1; }
            run += counts[e];
        }
        *nt1 = n1;
    }
    __syncthreads();
    for (int p = tid; p < 2 * NTOK; p += blockDim.x) {
        int e = tok_idx[p];
        int s = atomicAdd(&cur[e], 1);
        pair_token[s] = p >> 1;
        pair_wt[s] = tok_wt[p];
        slot_of[p] = s;
    }
}

// ---------------- GEMM1: act = silu(X@w1^T)*(X@w3^T); BM=256 BN=64 BK=32, single-buf ----------------
// m97 cadence: vmcnt(0) -> bar -> MFMA -> lgkm(0) -> bar -> DMA(next).
// A swizzle g(r)=(r^(r>>2))&3 (64B rows, 2-way max); B swizzle (r&7) (128B rows, R7-verified 0-conflict).
__global__ __launch_bounds__(256, 2) void moe_gemm1(
    const __bf16* __restrict__ xb, const float* __restrict__ w1g,
    const float* __restrict__ w3g, const int* __restrict__ counts,
    const int* __restrict__ offsets, const int* __restrict__ pair_token,
    const int* __restrict__ t1e, const int* __restrict__ t1m,
    const int* __restrict__ nt1,
    __bf16* __restrict__ act)
{
    const int ty = blockIdx.y;
    if (ty >= *nt1) return;
    const int e = t1e[ty];
    const int m0 = t1m[ty];
    const int Me = counts[e];
    const int rows = min(256, Me - m0);
    const int slot0 = offsets[e] + m0;
    const int n0 = blockIdx.x * 64;

    __shared__ __align__(16) __bf16 As[256 * 32];   // 16 KB
    __shared__ __align__(16) float  B1s[64 * 32];   // 8 KB
    __shared__ __align__(16) float  B3s[64 * 32];   // 8 KB

    const int tid = threadIdx.x;
    const int lane = tid & 63;
    const int wv = tid >> 6;
    const int ln4 = lane >> 4;
    const int lr = lane & 15;
    const int wm = (wv >> 1) * 128;   // 2x2 waves, wave tile 128x32
    const int wn = (wv & 1) * 32;

    f32x4 acc1[8][2], acc3[8][2];
#pragma unroll
    for (int i = 0; i < 8; ++i)
#pragma unroll
        for (int j = 0; j < 2; ++j) {
            acc1[i][j] = (f32x4){0.f, 0.f, 0.f, 0.f};
            acc3[i][j] = (f32x4){0.f, 0.f, 0.f, 0.f};
        }

    // A: 1024 chunks of 16B (256 rows x 4); 4/thread. Source pre-swizzle sj=(c&3)^g(r).
    const char* asrc[4];
#pragma unroll
    for (int i = 0; i < 4; ++i) {
        int c = i * 256 + tid;
        int r = c >> 2;
        int rr = (r < rows) ? r : 0;
        int sj = (c & 3) ^ ((r ^ (r >> 2)) & 3);
        asrc[i] = (const char*)(xb + (size_t)pair_token[slot0 + rr] * HDIM) + sj * 16;
    }
    // B: 512 chunks per matrix (64 rows x 8); 2/thread. Source pre-swizzle sj=(c&7)^(r&7).
    const char* bsrc[2];
#pragma unroll
    for (int i = 0; i < 2; ++i) {
        int c = i * 256 + tid;
        int r = c >> 3;
        int sj = (c & 7) ^ (r & 7);
        bsrc[i] = (const char*)(w1g + ((size_t)e * FDIM + n0 + r) * HDIM) + sj * 16;
    }
    const ptrdiff_t d31b = (const char*)w3g - (const char*)w1g;

#define DMA_ALL1(K0) do { \
    _Pragma("unroll") \
    for (int i = 0; i < 4; ++i) \
        DMA16(asrc[i] + (size_t)(K0) * 64, (char*)As + (i * 256 + wv * 64) * 16); \
    _Pragma("unroll") \
    for (int i = 0; i < 2; ++i) { \
        DMA16(bsrc[i] + (size_t)(K0) * 128,        (char*)B1s + (i * 256 + wv * 64) * 16); \
        DMA16(bsrc[i] + d31b + (size_t)(K0) * 128, (char*)B3s + (i * 256 + wv * 64) * 16); \
    } } while (0)

    // swizzled read byte-offsets
    int aoff[8];
#pragma unroll
    for (int i = 0; i < 8; ++i) {
        int row = wm + i * 16 + lr;
        aoff[i] = row * 64 + ((ln4 ^ ((row ^ (row >> 2)) & 3)) * 16);
    }
    int blo[2], bhi[2];
#pragma unroll
    for (int i = 0; i < 2; ++i) {
        int row = wn + i * 16 + lr;
        blo[i] = row * 128 + (((ln4 * 2) ^ (row & 7)) * 16);
        bhi[i] = row * 128 + (((ln4 * 2 + 1) ^ (row & 7)) * 16);
    }

#define CMP1() do { \
    v8bf af[8], b1f[2], b3f[2]; \
    _Pragma("unroll") \
    for (int i = 0; i < 2; ++i) { \
        b1f[i] = pack8(*(const f32x4*)((const char*)B1s + blo[i]), \
                       *(const f32x4*)((const char*)B1s + bhi[i])); \
        b3f[i] = pack8(*(const f32x4*)((const char*)B3s + blo[i]), \
                       *(const f32x4*)((const char*)B3s + bhi[i])); } \
    _Pragma("unroll") \
    for (int i = 0; i < 8; ++i) af[i] = *(const v8bf*)((const char*)As + aoff[i]); \
    _Pragma("unroll") \
    for (int mi = 0; mi < 8; ++mi) { _Pragma("unroll") \
        for (int ni = 0; ni < 2; ++ni) { \
            acc1[mi][ni] = __builtin_amdgcn_mfma_f32_16x16x32_bf16(af[mi], b1f[ni], acc1[mi][ni], 0, 0, 0); \
            acc3[mi][ni] = __builtin_amdgcn_mfma_f32_16x16x32_bf16(af[mi], b3f[ni], acc3[mi][ni], 0, 0, 0); } } \
    } while (0)

    DMA_ALL1(0);
    for (int ks = 0; ks < HDIM / 32; ++ks) {
        WAITVM0();
        BARRIER();
        CMP1();
        WAITLGKM0();
        BARRIER();
        if (ks + 1 < HDIM / 32) DMA_ALL1(ks + 1);
    }
#undef DMA_ALL1
#undef CMP1

    const int rj = ln4 * 4;
#pragma unroll
    for (int mi = 0; mi < 8; ++mi) {
#pragma unroll
        for (int j = 0; j < 4; ++j) {
            int rm = wm + mi * 16 + rj + j;
            if (rm < rows) {
                size_t rowoff = (size_t)(slot0 + rm) * FDIM + n0 + wn;
#pragma unroll
                for (int ni = 0; ni < 2; ++ni) {
                    float h1 = acc1[mi][ni][j];
                    float h3 = acc3[mi][ni][j];
                    float sv = (h1 / (1.f + __expf(-h1))) * h3;
                    act[rowoff + ni * 16 + lr] = (__bf16)sv;
                }
            }
        }
    }
}

// ---------------- GEMM2: y_part = act @ w2^T; BM=256 BN=64 BK=32, split-K x4 ----------------
__global__ __launch_bounds__(256, 2) void moe_gemm2(
    const __bf16* __restrict__ act, const float* __restrict__ w2g,
    const int* __restrict__ counts, const int* __restrict__ offsets,
    const int* __restrict__ t1e, const int* __restrict__ t1m,
    const int* __restrict__ nt1,
    float* __restrict__ y)
{
    const int ty = blockIdx.y;
    if (ty >= *nt1) return;
    const int e = t1e[ty];
    const int m0 = t1m[ty];
    const int Me = counts[e];
    const int rows = min(256, Me - m0);
    const int slot0 = offsets[e] + m0;
    const int n0 = blockIdx.x * 64;
    const int kz = blockIdx.z;
    float* yout = y + (size_t)kz * YSTRIDE;
    const size_t kbase = (size_t)kz * KPER2;

    __shared__ __align__(16) __bf16 As[256 * 32];   // 16 KB
    __shared__ __align__(16) float  Bs[64 * 32];    // 8 KB

    const int tid = threadIdx.x;
    const int lane = tid & 63;
    const int wv = tid >> 6;
    const int ln4 = lane >> 4;
    const int lr = lane & 15;
    const int wm = (wv >> 1) * 128;
    const int wn = (wv & 1) * 32;

    f32x4 acc[8][2];
#pragma unroll
    for (int i = 0; i < 8; ++i)
#pragma unroll
        for (int j = 0; j < 2; ++j) acc[i][j] = (f32x4){0.f, 0.f, 0.f, 0.f};

    const char* asrc[4];
#pragma unroll
    for (int i = 0; i < 4; ++i) {
        int c = i * 256 + tid;
        int r = c >> 2;
        int rr = (r < rows) ? r : 0;
        int sj = (c & 3) ^ ((r ^ (r >> 2)) & 3);
        asrc[i] = (const char*)(act + (size_t)(slot0 + rr) * FDIM + kbase) + sj * 16;
    }
    const char* bsrc[2];
#pragma unroll
    for (int i = 0; i < 2; ++i) {
        int c = i * 256 + tid;
        int r = c >> 3;
        int sj = (c & 7) ^ (r & 7);
        bsrc[i] = (const char*)(w2g + ((size_t)e * HDIM + n0 + r) * FDIM + kbase) + sj * 16;
    }

#define DMA_ALL2(K0) do { \
    _Pragma("unroll") \
    for (int i = 0; i < 4; ++i) \
        DMA16(asrc[i] + (size_t)(K0) * 64, (char*)As + (i * 256 + wv * 64) * 16); \
    _Pragma("unroll") \
    for (int i = 0; i < 2; ++i) \
        DMA16(bsrc[i] + (size_t)(K0) * 128, (char*)Bs + (i * 256 + wv * 64) * 16); \
    } while (0)

    int aoff[8];
#pragma unroll
    for (int i = 0; i < 8; ++i) {
        int row = wm + i * 16 + lr;
        aoff[i] = row * 64 + ((ln4 ^ ((row ^ (row >> 2)) & 3)) * 16);
    }
    int blo[2], bhi[2];
#pragma unroll
    for (int i = 0; i < 2; ++i) {
        int row = wn + i * 16 + lr;
        blo[i] = row * 128 + (((ln4 * 2) ^ (row & 7)) * 16);
        bhi[i] = row * 128 + (((ln4 * 2 + 1) ^ (row & 7)) * 16);
    }

#define CMP2() do { \
    v8bf af[8], bf[2]; \
    _Pragma("unroll") \
    for (int i = 0; i < 2; ++i) \
        bf[i] = pack8(*(const f32x4*)((const char*)Bs + blo[i]), \
                      *(const f32x4*)((const char*)Bs + bhi[i])); \
    _Pragma("unroll") \
    for (int i = 0; i < 8; ++i) af[i] = *(const v8bf*)((const char*)As + aoff[i]); \
    _Pragma("unroll") \
    for (int mi = 0; mi < 8; ++mi) { _Pragma("unroll") \
        for (int ni = 0; ni < 2; ++ni) \
            acc[mi][ni] = __builtin_amdgcn_mfma_f32_16x16x32_bf16(af[mi], bf[ni], acc[mi][ni], 0, 0, 0); } \
    } while (0)

    DMA_ALL2(0);
    for (int ks = 0; ks < KPER2 / 32; ++ks) {
        WAITVM0();
        BARRIER();
        CMP2();
        WAITLGKM0();
        BARRIER();
        if (ks + 1 < KPER2 / 32) DMA_ALL2(ks + 1);
    }
#undef DMA_ALL2
#undef CMP2

    const int rj = ln4 * 4;
#pragma unroll
    for (int mi = 0; mi < 8; ++mi) {
#pragma unroll
        for (int j = 0; j < 4; ++j) {
            int rm = wm + mi * 16 + rj + j;
            if (rm < rows) {
                size_t rowoff = (size_t)(slot0 + rm) * HDIM + n0 + wn;
#pragma unroll
                for (int ni = 0; ni < 2; ++ni)
                    yout[rowoff + ni * 16 + lr] = acc[mi][ni][j];
            }
        }
    }
}

// ---------------- combine: out[t] = sum_kz( w0*y[s0] + w1*y[s1] ) ----------------
__global__ __launch_bounds__(256) void moe_combine(
    const float* __restrict__ y, const int* __restrict__ slot_of,
    const float* __restrict__ pair_wt, float* __restrict__ out)
{
    const int t = blockIdx.x;
    const int tid = threadIdx.x;
    const int s0 = slot_of[2 * t];
    const int s1 = slot_of[2 * t + 1];
    const float w0 = pair_wt[s0];
    const float w1 = pair_wt[s1];
    float4 a = {0.f, 0.f, 0.f, 0.f}, b = {0.f, 0.f, 0.f, 0.f};
#pragma unroll
    for (int k = 0; k < KSPLIT2; ++k) {
        const float4 ak = *(const float4*)(y + k * YSTRIDE + (size_t)s0 * HDIM + tid * 4);
        const float4 bk = *(const float4*)(y + k * YSTRIDE + (size_t)s1 * HDIM + tid * 4);
        a.x += ak.x; a.y += ak.y; a.z += ak.z; a.w += ak.w;
        b.x += bk.x; b.y += bk.y; b.z += bk.z; b.w += bk.w;
    }
    float4 o;
    o.x = w0 * a.x + w1 * b.x;
    o.y = w0 * a.y + w1 * b.y;
    o.z = w0 * a.z + w1 * b.z;
    o.w = w0 * a.w + w1 * b.w;
    *(float4*)(out + (size_t)t * HDIM + tid * 4) = o;
}

extern "C" void kernel_launch(void* const* d_in, const int* in_sizes, int n_in,
                              void* d_out, int out_size, void* d_ws, size_t ws_size,
                              hipStream_t stream) {
    const float* x   = (const float*)d_in[0];
    const float* gw  = (const float*)d_in[1];
    const float* w1  = (const float*)d_in[2];
    const float* w2  = (const float*)d_in[3];
    const float* w3  = (const float*)d_in[4];

    float* out    = (float*)d_out;
    float* logits = out + (size_t)NTOK * HDIM;

    char* ws = (char*)d_ws;
    int*    counts     = (int*)(ws + OFF_COUNTS);
    int*    offsets    = (int*)(ws + OFF_OFFSETS);
    int*    nt1        = (int*)(ws + OFF_NT1);
    int*    t1e        = (int*)(ws + OFF_T1E);
    int*    t1m        = (int*)(ws + OFF_T1M);
    int*    tok_idx    = (int*)(ws + OFF_TOKIDX);
    float*  tok_wt     = (float*)(ws + OFF_TOKWT);
    int*    pair_token = (int*)(ws + OFF_PAIRTOK);
    float*  pair_wt    = (float*)(ws + OFF_PAIRWT);
    int*    slot_of    = (int*)(ws + OFF_SLOTOF);
    __bf16* xb         = (__bf16*)(ws + OFF_XB);
    __bf16* act        = (__bf16*)(ws + OFF_ACT);
    float*  yb         = (float*)(ws + OFF_Y);

    hipMemsetAsync(counts, 0, 64, stream);

    moe_cvtx<<<dim3(NTOK * HDIM / 1024), dim3(256), 0, stream>>>(x, xb);
    moe_router<<<dim3(NTOK / 4), dim3(256), 0, stream>>>(x, gw, logits, counts, tok_idx, tok_wt);
    moe_scatter<<<dim3(1), dim3(256), 0, stream>>>(counts, tok_idx, tok_wt, offsets,
                                                   pair_token, pair_wt, slot_of,
                                                   t1e, t1m, nt1);
    moe_gemm1<<<dim3(FDIM / 64, MAXT), dim3(256), 0, stream>>>(
        xb, w1, w3, counts, offsets, pair_token, t1e, t1m, nt1, act);
    moe_gemm2<<<dim3(HDIM / 64, MAXT, KSPLIT2), dim3(256), 0, stream>>>(
        act, w2, counts, offsets, t1e, t1m, nt1, yb);
    moe_combine<<<dim3(NTOK), dim3(256), 0, stream>>>(yb, slot_of, pair_wt, out);
}

// Round 11
// 192.957 us; speedup vs baseline: 1.7717x; 1.2351x over previous
//
#include <hip/hip_runtime.h>
#include <hip/hip_bf16.h>

typedef __bf16 v8bf __attribute__((ext_vector_type(8)));
typedef __bf16 v4bf __attribute__((ext_vector_type(4)));
typedef float  f32x4 __attribute__((ext_vector_type(4)));
typedef unsigned int u32;

#define NTOK 1024
#define HDIM 1024
#define FDIM 3584
#define NEXP 8
#define NPAIR 2048
#define MAXT 32          // BM=128 tiles
#define KSPLIT2 4
#define KPER2 (FDIM / KSPLIT2)   // 896

// workspace layout (bytes)
#define OFF_COUNTS   0
#define OFF_OFFSETS  64
#define OFF_NT1      128
#define OFF_T1E      192
#define OFF_T1M      320
#define OFF_TOKIDX   2048
#define OFF_TOKWT    (2048 + 4*NPAIR)
#define OFF_PAIRTOK  (OFF_TOKWT + 4*NPAIR)
#define OFF_PAIRWT   (OFF_PAIRTOK + 4*NPAIR)
#define OFF_SLOTOF   (OFF_PAIRWT + 4*NPAIR)
#define OFF_XB       65536                          // bf16 [1024][1024] = 2 MB
#define OFF_ACT      (OFF_XB + 2ull*NTOK*HDIM)      // bf16 [2048][3584]
#define OFF_Y        (OFF_ACT + 2ull*NPAIR*FDIM)    // f32  [4][2048][1024]
#define YSTRIDE      ((size_t)NPAIR * HDIM)

static __device__ inline v4bf cvt4(float4 f) {
    v4bf r;
    r[0] = (__bf16)f.x; r[1] = (__bf16)f.y; r[2] = (__bf16)f.z; r[3] = (__bf16)f.w;
    return r;
}

static __device__ inline v8bf pack8(f32x4 lo, f32x4 hi) {
    v8bf r;
    r[0] = (__bf16)lo[0]; r[1] = (__bf16)lo[1]; r[2] = (__bf16)lo[2]; r[3] = (__bf16)lo[3];
    r[4] = (__bf16)hi[0]; r[5] = (__bf16)hi[1]; r[6] = (__bf16)hi[2]; r[7] = (__bf16)hi[3];
    return r;
}

#define FENCE() asm volatile("" ::: "memory")
#define BARRIER() do { FENCE(); __builtin_amdgcn_s_barrier(); FENCE(); } while (0)
#define WAITVM0() asm volatile("s_waitcnt vmcnt(0)" ::: "memory")
#define WAITLGKM0() asm volatile("s_waitcnt lgkmcnt(0)" ::: "memory")

#define DMA16(SRC, DST) \
    __builtin_amdgcn_global_load_lds((const __attribute__((address_space(1))) u32*)(SRC), \
                                     (__attribute__((address_space(3))) u32*)(DST), 16, 0, 0)

// ---------------- x -> bf16 ----------------
__global__ __launch_bounds__(256) void moe_cvtx(const float* __restrict__ x,
                                                __bf16* __restrict__ xb)
{
    const size_t i = ((size_t)blockIdx.x * 256 + threadIdx.x) * 4;
    float4 v = *(const float4*)(x + i);
    *(v4bf*)(xb + i) = cvt4(v);
}

// ---------------- router ----------------
__global__ __launch_bounds__(256) void moe_router(
    const float* __restrict__ x, const float* __restrict__ gw,
    float* __restrict__ logits, int* __restrict__ counts,
    int* __restrict__ tok_idx, float* __restrict__ tok_wt)
{
    const int lane = threadIdx.x & 63;
    const int wv = threadIdx.x >> 6;
    const int t = blockIdx.x * 4 + wv;
    const float* xr = x + (size_t)t * HDIM;

    float acc[NEXP];
#pragma unroll
    for (int e = 0; e < NEXP; ++e) acc[e] = 0.f;
#pragma unroll
    for (int j = 0; j < 4; ++j) {
        int h = lane * 4 + j * 256;
        float4 xv = *(const float4*)(xr + h);
#pragma unroll
        for (int e = 0; e < NEXP; ++e) {
            float4 g = *(const float4*)(gw + e * HDIM + h);
            acc[e] += xv.x * g.x + xv.y * g.y + xv.z * g.z + xv.w * g.w;
        }
    }
#pragma unroll
    for (int e = 0; e < NEXP; ++e) {
#pragma unroll
        for (int s = 32; s > 0; s >>= 1) acc[e] += __shfl_xor(acc[e], s);
    }
    if (lane == 0) {
#pragma unroll
        for (int e = 0; e < NEXP; ++e) logits[t * NEXP + e] = acc[e];
        int i0 = 0;
#pragma unroll
        for (int e = 1; e < NEXP; ++e) if (acc[e] > acc[i0]) i0 = e;
        int i1 = (i0 == 0) ? 1 : 0;
#pragma unroll
        for (int e = 0; e < NEXP; ++e) if (e != i0 && acc[e] > acc[i1]) i1 = e;
        float w0 = 1.f / (1.f + expf(acc[i1] - acc[i0]));
        float w1 = 1.f - w0;
        tok_idx[2 * t] = i0; tok_idx[2 * t + 1] = i1;
        tok_wt[2 * t] = w0;  tok_wt[2 * t + 1] = w1;
        atomicAdd(&counts[i0], 1);
        atomicAdd(&counts[i1], 1);
    }
}

// ---------------- scatter + tile list (BM=128) ----------------
__global__ void moe_scatter(const int* __restrict__ counts, const int* __restrict__ tok_idx,
                            const float* __restrict__ tok_wt, int* __restrict__ offsets,
                            int* __restrict__ pair_token, float* __restrict__ pair_wt,
                            int* __restrict__ slot_of,
                            int* __restrict__ t1e, int* __restrict__ t1m, int* __restrict__ nt1)
{
    __shared__ int cur[NEXP];
    const int tid = threadIdx.x;
    if (tid == 0) {
        int run = 0, n1 = 0;
        for (int e = 0; e < NEXP; ++e) {
            offsets[e] = run; cur[e] = run;
            for (int m0 = 0; m0 < counts[e]; m0 += 128) { t1e[n1] = e; t1m[n1] = m0; ++n1; }
            run += counts[e];
        }
        *nt1 = n1;
    }
    __syncthreads();
    for (int p = tid; p < 2 * NTOK; p += blockDim.x) {
        int e = tok_idx[p];
        int s = atomicAdd(&cur[e], 1);
        pair_token[s] = p >> 1;
        pair_wt[s] = tok_wt[p];
        slot_of[p] = s;
    }
}

// ---------------- GEMM1: act = silu(X@w1^T)*(X@w3^T); BM=128 BN=64 BK=64, single-buf ----------------
// R7-verified structure (0 bank conflicts), now at 3 blocks/CU.
__global__ __launch_bounds__(256, 3) void moe_gemm1(
    const __bf16* __restrict__ xb, const float* __restrict__ w1g,
    const float* __restrict__ w3g, const int* __restrict__ counts,
    const int* __restrict__ offsets, const int* __restrict__ pair_token,
    const int* __restrict__ t1e, const int* __restrict__ t1m,
    const int* __restrict__ nt1,
    __bf16* __restrict__ act)
{
    const int ty = blockIdx.y;
    if (ty >= *nt1) return;
    const int e = t1e[ty];
    const int m0 = t1m[ty];
    const int Me = counts[e];
    const int rows = min(128, Me - m0);
    const int slot0 = offsets[e] + m0;
    const int n0 = blockIdx.x * 64;

    __shared__ __align__(16) __bf16 As[128 * 64];    // 16 KB
    __shared__ __align__(16) float  B1s[64 * 64];    // 16 KB
    __shared__ __align__(16) float  B3s[64 * 64];    // 16 KB

    const int tid = threadIdx.x;
    const int lane = tid & 63;
    const int wv = tid >> 6;
    const int ln4 = lane >> 4;
    const int lr = lane & 15;
    const int wm = (wv >> 1) * 64;
    const int wn = (wv & 1) * 32;

    f32x4 acc1[4][2], acc3[4][2];
#pragma unroll
    for (int i = 0; i < 4; ++i)
#pragma unroll
        for (int j = 0; j < 2; ++j) {
            acc1[i][j] = (f32x4){0.f, 0.f, 0.f, 0.f};
            acc3[i][j] = (f32x4){0.f, 0.f, 0.f, 0.f};
        }

    // A: 1024 chunks of 16B (128 rows x 8 chunks); 4/thread; src pre-swizzle (c&7)^(r&7)
    const char* asrc[4];
#pragma unroll
    for (int i = 0; i < 4; ++i) {
        int c = i * 256 + tid;
        int r = c >> 3;
        int rr = (r < rows) ? r : 0;
        int sj = (c & 7) ^ (r & 7);
        asrc[i] = (const char*)(xb + (size_t)pair_token[slot0 + rr] * HDIM) + sj * 16;
    }
    // B: 1024 chunks per matrix (64 rows x 16 chunks); 4/thread/matrix; src pre-swizzle (c&15)^(r&15)
    const char* bsrc[4];
#pragma unroll
    for (int i = 0; i < 4; ++i) {
        int c = i * 256 + tid;
        int r = c >> 4;
        int sj = (c & 15) ^ (r & 15);
        bsrc[i] = (const char*)(w1g + ((size_t)e * FDIM + n0 + r) * HDIM) + sj * 16;
    }
    const ptrdiff_t d31b = (const char*)w3g - (const char*)w1g;

#define DMA_ALL1(K0) do { _Pragma("unroll") \
    for (int i = 0; i < 4; ++i) { \
        DMA16(asrc[i] + (size_t)(K0) * 128, (char*)As + (i * 256 + wv * 64) * 16); \
        DMA16(bsrc[i] + (size_t)(K0) * 256, (char*)B1s + (i * 256 + wv * 64) * 16); \
        DMA16(bsrc[i] + d31b + (size_t)(K0) * 256, (char*)B3s + (i * 256 + wv * 64) * 16); \
    } } while (0)

    int abase[4], axor[4];
#pragma unroll
    for (int i = 0; i < 4; ++i) {
        int row = wm + i * 16 + lr;
        abase[i] = row * 128;
        axor[i] = (row & 7) << 4;
    }
    int bbase[2], bxor[2];
#pragma unroll
    for (int i = 0; i < 2; ++i) {
        int row = wn + i * 16 + lr;
        bbase[i] = row * 256;
        bxor[i] = (row & 15) << 4;
    }

#define CMP1() do { \
    v8bf af[4][2]; v8bf b1f[2][2], b3f[2][2]; \
    _Pragma("unroll") \
    for (int mi = 0; mi < 4; ++mi) { _Pragma("unroll") \
        for (int ks = 0; ks < 2; ++ks) \
            af[mi][ks] = *(const v8bf*)((const char*)As + abase[mi] + ((ks * 64 + ln4 * 16) ^ axor[mi])); } \
    _Pragma("unroll") \
    for (int ni = 0; ni < 2; ++ni) { _Pragma("unroll") \
        for (int ks = 0; ks < 2; ++ks) { \
            int in0 = ks * 128 + ln4 * 32; \
            f32x4 lo1 = *(const f32x4*)((const char*)B1s + bbase[ni] + ((in0) ^ bxor[ni])); \
            f32x4 hi1 = *(const f32x4*)((const char*)B1s + bbase[ni] + ((in0 + 16) ^ bxor[ni])); \
            f32x4 lo3 = *(const f32x4*)((const char*)B3s + bbase[ni] + ((in0) ^ bxor[ni])); \
            f32x4 hi3 = *(const f32x4*)((const char*)B3s + bbase[ni] + ((in0 + 16) ^ bxor[ni])); \
            b1f[ni][ks] = pack8(lo1, hi1); \
            b3f[ni][ks] = pack8(lo3, hi3); } } \
    _Pragma("unroll") \
    for (int mi = 0; mi < 4; ++mi) { _Pragma("unroll") \
        for (int ni = 0; ni < 2; ++ni) { _Pragma("unroll") \
            for (int ks = 0; ks < 2; ++ks) { \
                acc1[mi][ni] = __builtin_amdgcn_mfma_f32_16x16x32_bf16(af[mi][ks], b1f[ni][ks], acc1[mi][ni], 0, 0, 0); \
                acc3[mi][ni] = __builtin_amdgcn_mfma_f32_16x16x32_bf16(af[mi][ks], b3f[ni][ks], acc3[mi][ni], 0, 0, 0); } } } \
    } while (0)

    DMA_ALL1(0);
    for (int ks = 0; ks < HDIM / 64; ++ks) {
        WAITVM0();
        BARRIER();
        CMP1();
        WAITLGKM0();
        BARRIER();
        if (ks + 1 < HDIM / 64) DMA_ALL1(ks + 1);
    }
#undef DMA_ALL1
#undef CMP1

    const int rj = ln4 * 4;
#pragma unroll
    for (int mi = 0; mi < 4; ++mi) {
#pragma unroll
        for (int j = 0; j < 4; ++j) {
            int rm = wm + mi * 16 + rj + j;
            if (rm < rows) {
                size_t rowoff = (size_t)(slot0 + rm) * FDIM + n0 + wn;
#pragma unroll
                for (int ni = 0; ni < 2; ++ni) {
                    float h1 = acc1[mi][ni][j];
                    float h3 = acc3[mi][ni][j];
                    float sv = (h1 / (1.f + __expf(-h1))) * h3;
                    act[rowoff + ni * 16 + lr] = (__bf16)sv;
                }
            }
        }
    }
}

// ---------------- GEMM2: y_part = act @ w2^T; BM=128 BN=64 BK=64, split-K x4, single-buf ----------------
__global__ __launch_bounds__(256, 4) void moe_gemm2(
    const __bf16* __restrict__ act, const float* __restrict__ w2g,
    const int* __restrict__ counts, const int* __restrict__ offsets,
    const int* __restrict__ t1e, const int* __restrict__ t1m,
    const int* __restrict__ nt1,
    float* __restrict__ y)
{
    const int ty = blockIdx.y;
    if (ty >= *nt1) return;
    const int e = t1e[ty];
    const int m0 = t1m[ty];
    const int Me = counts[e];
    const int rows = min(128, Me - m0);
    const int slot0 = offsets[e] + m0;
    const int n0 = blockIdx.x * 64;
    const int kz = blockIdx.z;
    float* yout = y + (size_t)kz * YSTRIDE;
    const size_t kbase = (size_t)kz * KPER2;

    __shared__ __align__(16) __bf16 As[128 * 64];   // 16 KB
    __shared__ __align__(16) float  Bs[64 * 64];    // 16 KB

    const int tid = threadIdx.x;
    const int lane = tid & 63;
    const int wv = tid >> 6;
    const int ln4 = lane >> 4;
    const int lr = lane & 15;
    const int wm = (wv >> 1) * 64;
    const int wn = (wv & 1) * 32;

    f32x4 acc[4][2];
#pragma unroll
    for (int i = 0; i < 4; ++i)
#pragma unroll
        for (int j = 0; j < 2; ++j) acc[i][j] = (f32x4){0.f, 0.f, 0.f, 0.f};

    // A: 1024 chunks (128 rows x 8); 4/thread; pre-swizzle (c&7)^(r&7)
    const char* asrc[4];
#pragma unroll
    for (int i = 0; i < 4; ++i) {
        int c = i * 256 + tid;
        int r = c >> 3;
        int rr = (r < rows) ? r : 0;
        int sj = (c & 7) ^ (r & 7);
        asrc[i] = (const char*)(act + (size_t)(slot0 + rr) * FDIM + kbase) + sj * 16;
    }
    // B: 1024 chunks (64 rows x 16); 4/thread; pre-swizzle (c&15)^(r&15)
    const char* bsrc[4];
#pragma unroll
    for (int i = 0; i < 4; ++i) {
        int c = i * 256 + tid;
        int r = c >> 4;
        int sj = (c & 15) ^ (r & 15);
        bsrc[i] = (const char*)(w2g + ((size_t)e * HDIM + n0 + r) * FDIM + kbase) + sj * 16;
    }

#define DMA_ALL2(K0) do { _Pragma("unroll") \
    for (int i = 0; i < 4; ++i) { \
        DMA16(asrc[i] + (size_t)(K0) * 128, (char*)As + (i * 256 + wv * 64) * 16); \
        DMA16(bsrc[i] + (size_t)(K0) * 256, (char*)Bs + (i * 256 + wv * 64) * 16); \
    } } while (0)

    int abase[4], axor[4];
#pragma unroll
    for (int i = 0; i < 4; ++i) {
        int row = wm + i * 16 + lr;
        abase[i] = row * 128;
        axor[i] = (row & 7) << 4;
    }
    int bbase[2], bxor[2];
#pragma unroll
    for (int i = 0; i < 2; ++i) {
        int row = wn + i * 16 + lr;
        bbase[i] = row * 256;
        bxor[i] = (row & 15) << 4;
    }

#define CMP2() do { \
    v8bf af[4][2], bf[2][2]; \
    _Pragma("unroll") \
    for (int mi = 0; mi < 4; ++mi) { _Pragma("unroll") \
        for (int ks = 0; ks < 2; ++ks) \
            af[mi][ks] = *(const v8bf*)((const char*)As + abase[mi] + ((ks * 64 + ln4 * 16) ^ axor[mi])); } \
    _Pragma("unroll") \
    for (int ni = 0; ni < 2; ++ni) { _Pragma("unroll") \
        for (int ks = 0; ks < 2; ++ks) { \
            int in0 = ks * 128 + ln4 * 32; \
            f32x4 lo = *(const f32x4*)((const char*)Bs + bbase[ni] + ((in0) ^ bxor[ni])); \
            f32x4 hi = *(const f32x4*)((const char*)Bs + bbase[ni] + ((in0 + 16) ^ bxor[ni])); \
            bf[ni][ks] = pack8(lo, hi); } } \
    _Pragma("unroll") \
    for (int mi = 0; mi < 4; ++mi) { _Pragma("unroll") \
        for (int ni = 0; ni < 2; ++ni) { _Pragma("unroll") \
            for (int ks = 0; ks < 2; ++ks) \
                acc[mi][ni] = __builtin_amdgcn_mfma_f32_16x16x32_bf16(af[mi][ks], bf[ni][ks], acc[mi][ni], 0, 0, 0); } } \
    } while (0)

    DMA_ALL2(0);
    for (int ks = 0; ks < KPER2 / 64; ++ks) {
        WAITVM0();
        BARRIER();
        CMP2();
        WAITLGKM0();
        BARRIER();
        if (ks + 1 < KPER2 / 64) DMA_ALL2(ks + 1);
    }
#undef DMA_ALL2
#undef CMP2

    const int rj = ln4 * 4;
#pragma unroll
    for (int mi = 0; mi < 4; ++mi) {
#pragma unroll
        for (int j = 0; j < 4; ++j) {
            int rm = wm + mi * 16 + rj + j;
            if (rm < rows) {
                size_t rowoff = (size_t)(slot0 + rm) * HDIM + n0 + wn;
#pragma unroll
                for (int ni = 0; ni < 2; ++ni)
                    yout[rowoff + ni * 16 + lr] = acc[mi][ni][j];
            }
        }
    }
}

// ---------------- combine: out[t] = sum_kz( w0*y[s0] + w1*y[s1] ) ----------------
__global__ __launch_bounds__(256) void moe_combine(
    const float* __restrict__ y, const int* __restrict__ slot_of,
    const float* __restrict__ pair_wt, float* __restrict__ out)
{
    const int t = blockIdx.x;
    const int tid = threadIdx.x;
    const int s0 = slot_of[2 * t];
    const int s1 = slot_of[2 * t + 1];
    const float w0 = pair_wt[s0];
    const float w1 = pair_wt[s1];
    float4 a = {0.f, 0.f, 0.f, 0.f}, b = {0.f, 0.f, 0.f, 0.f};
#pragma unroll
    for (int k = 0; k < KSPLIT2; ++k) {
        const float4 ak = *(const float4*)(y + k * YSTRIDE + (size_t)s0 * HDIM + tid * 4);
        const float4 bk = *(const float4*)(y + k * YSTRIDE + (size_t)s1 * HDIM + tid * 4);
        a.x += ak.x; a.y += ak.y; a.z += ak.z; a.w += ak.w;
        b.x += bk.x; b.y += bk.y; b.z += bk.z; b.w += bk.w;
    }
    float4 o;
    o.x = w0 * a.x + w1 * b.x;
    o.y = w0 * a.y + w1 * b.y;
    o.z = w0 * a.z + w1 * b.z;
    o.w = w0 * a.w + w1 * b.w;
    *(float4*)(out + (size_t)t * HDIM + tid * 4) = o;
}

extern "C" void kernel_launch(void* const* d_in, const int* in_sizes, int n_in,
                              void* d_out, int out_size, void* d_ws, size_t ws_size,
                              hipStream_t stream) {
    const float* x   = (const float*)d_in[0];
    const float* gw  = (const float*)d_in[1];
    const float* w1  = (const float*)d_in[2];
    const float* w2  = (const float*)d_in[3];
    const float* w3  = (const float*)d_in[4];

    float* out    = (float*)d_out;
    float* logits = out + (size_t)NTOK * HDIM;

    char* ws = (char*)d_ws;
    int*    counts     = (int*)(ws + OFF_COUNTS);
    int*    offsets    = (int*)(ws + OFF_OFFSETS);
    int*    nt1        = (int*)(ws + OFF_NT1);
    int*    t1e        = (int*)(ws + OFF_T1E);
    int*    t1m        = (int*)(ws + OFF_T1M);
    int*    tok_idx    = (int*)(ws + OFF_TOKIDX);
    float*  tok_wt     = (float*)(ws + OFF_TOKWT);
    int*    pair_token = (int*)(ws + OFF_PAIRTOK);
    float*  pair_wt    = (float*)(ws + OFF_PAIRWT);
    int*    slot_of    = (int*)(ws + OFF_SLOTOF);
    __bf16* xb         = (__bf16*)(ws + OFF_XB);
    __bf16* act        = (__bf16*)(ws + OFF_ACT);
    float*  yb         = (float*)(ws + OFF_Y);

    hipMemsetAsync(counts, 0, 64, stream);

    moe_cvtx<<<dim3(NTOK * HDIM / 1024), dim3(256), 0, stream>>>(x, xb);
    moe_router<<<dim3(NTOK / 4), dim3(256), 0, stream>>>(x, gw, logits, counts, tok_idx, tok_wt);
    moe_scatter<<<dim3(1), dim3(256), 0, stream>>>(counts, tok_idx, tok_wt, offsets,
                                                   pair_token, pair_wt, slot_of,
                                                   t1e, t1m, nt1);
    moe_gemm1<<<dim3(FDIM / 64, MAXT), dim3(256), 0, stream>>>(
        xb, w1, w3, counts, offsets, pair_token, t1e, t1m, nt1, act);
    moe_gemm2<<<dim3(HDIM / 64, MAXT, KSPLIT2), dim3(256), 0, stream>>>(
        act, w2, counts, offsets, t1e, t1m, nt1, yb);
    moe_combine<<<dim3(NTOK), dim3(256), 0, stream>>>(yb, slot_of, pair_wt, out);
}

// Round 12
// 192.078 us; speedup vs baseline: 1.7798x; 1.0046x over previous
//
#include <hip/hip_runtime.h>
#include <hip/hip_bf16.h>

typedef __bf16 v8bf __attribute__((ext_vector_type(8)));
typedef __bf16 v4bf __attribute__((ext_vector_type(4)));
typedef float  f32x4 __attribute__((ext_vector_type(4)));
typedef unsigned int u32;

#define NTOK 1024
#define HDIM 1024
#define FDIM 3584
#define NEXP 8
#define NPAIR 2048
#define MAXT 16          // BM=256 tiles
#define KSPLIT2 4
#define KPER2 (FDIM / KSPLIT2)   // 896

// workspace layout (bytes)
#define OFF_COUNTS   0
#define OFF_OFFSETS  64
#define OFF_NT1      128
#define OFF_T1E      192
#define OFF_T1M      320
#define OFF_TOKIDX   2048
#define OFF_TOKWT    (2048 + 4*NPAIR)
#define OFF_PAIRTOK  (OFF_TOKWT + 4*NPAIR)
#define OFF_PAIRWT   (OFF_PAIRTOK + 4*NPAIR)
#define OFF_SLOTOF   (OFF_PAIRWT + 4*NPAIR)
#define OFF_XB       65536                          // bf16 [1024][1024] = 2 MB (L2-resident)
#define OFF_ACT      (OFF_XB + 2ull*NTOK*HDIM)      // bf16 [2048][3584]
#define OFF_Y        (OFF_ACT + 2ull*NPAIR*FDIM)    // f32  [4][2048][1024]
#define YSTRIDE      ((size_t)NPAIR * HDIM)

static __device__ inline v4bf cvt4(float4 f) {
    v4bf r;
    r[0] = (__bf16)f.x; r[1] = (__bf16)f.y; r[2] = (__bf16)f.z; r[3] = (__bf16)f.w;
    return r;
}

static __device__ inline v8bf pack8(f32x4 lo, f32x4 hi) {
    v8bf r;
    r[0] = (__bf16)lo[0]; r[1] = (__bf16)lo[1]; r[2] = (__bf16)lo[2]; r[3] = (__bf16)lo[3];
    r[4] = (__bf16)hi[0]; r[5] = (__bf16)hi[1]; r[6] = (__bf16)hi[2]; r[7] = (__bf16)hi[3];
    return r;
}

#define FENCE() asm volatile("" ::: "memory")
#define BARRIER() do { FENCE(); __builtin_amdgcn_s_barrier(); FENCE(); } while (0)
#define WAITVM0() asm volatile("s_waitcnt vmcnt(0)" ::: "memory")
#define WAITLGKM0() asm volatile("s_waitcnt lgkmcnt(0)" ::: "memory")

#define DMA16(SRC, DST) \
    __builtin_amdgcn_global_load_lds((const __attribute__((address_space(1))) u32*)(SRC), \
                                     (__attribute__((address_space(3))) u32*)(DST), 16, 0, 0)

// ---------------- x -> bf16 ----------------
__global__ __launch_bounds__(256) void moe_cvtx(const float* __restrict__ x,
                                                __bf16* __restrict__ xb)
{
    const size_t i = ((size_t)blockIdx.x * 256 + threadIdx.x) * 4;
    float4 v = *(const float4*)(x + i);
    *(v4bf*)(xb + i) = cvt4(v);
}

// ---------------- router ----------------
__global__ __launch_bounds__(256) void moe_router(
    const float* __restrict__ x, const float* __restrict__ gw,
    float* __restrict__ logits, int* __restrict__ counts,
    int* __restrict__ tok_idx, float* __restrict__ tok_wt)
{
    const int lane = threadIdx.x & 63;
    const int wv = threadIdx.x >> 6;
    const int t = blockIdx.x * 4 + wv;
    const float* xr = x + (size_t)t * HDIM;

    float acc[NEXP];
#pragma unroll
    for (int e = 0; e < NEXP; ++e) acc[e] = 0.f;
#pragma unroll
    for (int j = 0; j < 4; ++j) {
        int h = lane * 4 + j * 256;
        float4 xv = *(const float4*)(xr + h);
#pragma unroll
        for (int e = 0; e < NEXP; ++e) {
            float4 g = *(const float4*)(gw + e * HDIM + h);
            acc[e] += xv.x * g.x + xv.y * g.y + xv.z * g.z + xv.w * g.w;
        }
    }
#pragma unroll
    for (int e = 0; e < NEXP; ++e) {
#pragma unroll
        for (int s = 32; s > 0; s >>= 1) acc[e] += __shfl_xor(acc[e], s);
    }
    if (lane == 0) {
#pragma unroll
        for (int e = 0; e < NEXP; ++e) logits[t * NEXP + e] = acc[e];
        int i0 = 0;
#pragma unroll
        for (int e = 1; e < NEXP; ++e) if (acc[e] > acc[i0]) i0 = e;
        int i1 = (i0 == 0) ? 1 : 0;
#pragma unroll
        for (int e = 0; e < NEXP; ++e) if (e != i0 && acc[e] > acc[i1]) i1 = e;
        float w0 = 1.f / (1.f + expf(acc[i1] - acc[i0]));
        float w1 = 1.f - w0;
        tok_idx[2 * t] = i0; tok_idx[2 * t + 1] = i1;
        tok_wt[2 * t] = w0;  tok_wt[2 * t + 1] = w1;
        atomicAdd(&counts[i0], 1);
        atomicAdd(&counts[i1], 1);
    }
}

// ---------------- scatter + tile list (BM=256) ----------------
__global__ void moe_scatter(const int* __restrict__ counts, const int* __restrict__ tok_idx,
                            const float* __restrict__ tok_wt, int* __restrict__ offsets,
                            int* __restrict__ pair_token, float* __restrict__ pair_wt,
                            int* __restrict__ slot_of,
                            int* __restrict__ t1e, int* __restrict__ t1m, int* __restrict__ nt1)
{
    __shared__ int cur[NEXP];
    const int tid = threadIdx.x;
    if (tid == 0) {
        int run = 0, n1 = 0;
        for (int e = 0; e < NEXP; ++e) {
            offsets[e] = run; cur[e] = run;
            for (int m0 = 0; m0 < counts[e]; m0 += 256) { t1e[n1] = e; t1m[n1] = m0; ++n1; }
            run += counts[e];
        }
        *nt1 = n1;
    }
    __syncthreads();
    for (int p = tid; p < 2 * NTOK; p += blockDim.x) {
        int e = tok_idx[p];
        int s = atomicAdd(&cur[e], 1);
        pair_token[s] = p >> 1;
        pair_wt[s] = tok_wt[p];
        slot_of[p] = s;
    }
}

// ---------------- GEMM1: act = silu(X@w1^T)*(X@w3^T); BM=256 BN=32 BK=64, single-buf ----------------
// Iso-cost with R7 (48KB/step, 32 MFMA/wave/step, 12 DMA/thread) but L3-served B bytes halved.
__global__ __launch_bounds__(256, 2) void moe_gemm1(
    const __bf16* __restrict__ xb, const float* __restrict__ w1g,
    const float* __restrict__ w3g, const int* __restrict__ counts,
    const int* __restrict__ offsets, const int* __restrict__ pair_token,
    const int* __restrict__ t1e, const int* __restrict__ t1m,
    const int* __restrict__ nt1,
    __bf16* __restrict__ act)
{
    const int ty = blockIdx.y;
    if (ty >= *nt1) return;
    const int e = t1e[ty];
    const int m0 = t1m[ty];
    const int Me = counts[e];
    const int rows = min(256, Me - m0);
    const int slot0 = offsets[e] + m0;
    const int n0 = blockIdx.x * 32;

    __shared__ __align__(16) __bf16 As[256 * 64];    // 32 KB
    __shared__ __align__(16) float  B1s[32 * 64];    // 8 KB
    __shared__ __align__(16) float  B3s[32 * 64];    // 8 KB

    const int tid = threadIdx.x;
    const int lane = tid & 63;
    const int wv = tid >> 6;
    const int ln4 = lane >> 4;
    const int lr = lane & 15;
    const int wm = (wv >> 1) * 128;   // 2m x 2n waves; wave tile 128x16
    const int wn = (wv & 1) * 16;

    f32x4 acc1[8], acc3[8];
#pragma unroll
    for (int i = 0; i < 8; ++i) {
        acc1[i] = (f32x4){0.f, 0.f, 0.f, 0.f};
        acc3[i] = (f32x4){0.f, 0.f, 0.f, 0.f};
    }

    // A: 2048 chunks of 16B (256 rows x 8 chunks/128B row); 8/thread; src pre-swizzle (c&7)^(r&7)
    const char* asrc[8];
#pragma unroll
    for (int i = 0; i < 8; ++i) {
        int c = i * 256 + tid;
        int r = c >> 3;
        int rr = (r < rows) ? r : 0;
        int sj = (c & 7) ^ (r & 7);
        asrc[i] = (const char*)(xb + (size_t)pair_token[slot0 + rr] * HDIM) + sj * 16;
    }
    // B: 512 chunks per matrix (32 rows x 16 chunks/256B row); 2/thread/matrix; pre-swizzle (c&15)^(r&15)
    const char* bsrc[2];
#pragma unroll
    for (int i = 0; i < 2; ++i) {
        int c = i * 256 + tid;
        int r = c >> 4;
        int sj = (c & 15) ^ (r & 15);
        bsrc[i] = (const char*)(w1g + ((size_t)e * FDIM + n0 + r) * HDIM) + sj * 16;
    }
    const ptrdiff_t d31b = (const char*)w3g - (const char*)w1g;

#define DMA_ALL1(K0) do { \
    _Pragma("unroll") \
    for (int i = 0; i < 8; ++i) \
        DMA16(asrc[i] + (size_t)(K0) * 128, (char*)As + (i * 256 + wv * 64) * 16); \
    _Pragma("unroll") \
    for (int i = 0; i < 2; ++i) { \
        DMA16(bsrc[i] + (size_t)(K0) * 256,        (char*)B1s + (i * 256 + wv * 64) * 16); \
        DMA16(bsrc[i] + d31b + (size_t)(K0) * 256, (char*)B3s + (i * 256 + wv * 64) * 16); \
    } } while (0)

    int abase[8], axor[8];
#pragma unroll
    for (int i = 0; i < 8; ++i) {
        int row = wm + i * 16 + lr;
        abase[i] = row * 128;
        axor[i] = (row & 7) << 4;
    }
    int bbase, bxor;
    {
        int row = wn + lr;
        bbase = row * 256;
        bxor = (row & 15) << 4;
    }

#define CMP1() do { \
    _Pragma("unroll") \
    for (int ksub = 0; ksub < 2; ++ksub) { \
        int in0 = ksub * 128 + ln4 * 32; \
        v8bf b1f = pack8(*(const f32x4*)((const char*)B1s + bbase + ((in0) ^ bxor)), \
                         *(const f32x4*)((const char*)B1s + bbase + ((in0 + 16) ^ bxor))); \
        v8bf b3f = pack8(*(const f32x4*)((const char*)B3s + bbase + ((in0) ^ bxor)), \
                         *(const f32x4*)((const char*)B3s + bbase + ((in0 + 16) ^ bxor))); \
        _Pragma("unroll") \
        for (int mi = 0; mi < 8; ++mi) { \
            v8bf af = *(const v8bf*)((const char*)As + abase[mi] + ((ksub * 64 + ln4 * 16) ^ axor[mi])); \
            acc1[mi] = __builtin_amdgcn_mfma_f32_16x16x32_bf16(af, b1f, acc1[mi], 0, 0, 0); \
            acc3[mi] = __builtin_amdgcn_mfma_f32_16x16x32_bf16(af, b3f, acc3[mi], 0, 0, 0); \
        } } } while (0)

    DMA_ALL1(0);
    for (int ks = 0; ks < HDIM / 64; ++ks) {
        WAITVM0();
        BARRIER();
        CMP1();
        WAITLGKM0();
        BARRIER();
        if (ks + 1 < HDIM / 64) DMA_ALL1(ks + 1);
    }
#undef DMA_ALL1
#undef CMP1

    const int rj = ln4 * 4;
#pragma unroll
    for (int mi = 0; mi < 8; ++mi) {
#pragma unroll
        for (int j = 0; j < 4; ++j) {
            int rm = wm + mi * 16 + rj + j;
            if (rm < rows) {
                size_t rowoff = (size_t)(slot0 + rm) * FDIM + n0 + wn;
                float h1 = acc1[mi][j];
                float h3 = acc3[mi][j];
                float sv = (h1 / (1.f + __expf(-h1))) * h3;
                act[rowoff + lr] = (__bf16)sv;
            }
        }
    }
}

// ---------------- GEMM2: y_part = act @ w2^T; BM=256 BN=64 BK=64, split-K x4, single-buf ----------------
__global__ __launch_bounds__(256, 2) void moe_gemm2(
    const __bf16* __restrict__ act, const float* __restrict__ w2g,
    const int* __restrict__ counts, const int* __restrict__ offsets,
    const int* __restrict__ t1e, const int* __restrict__ t1m,
    const int* __restrict__ nt1,
    float* __restrict__ y)
{
    const int ty = blockIdx.y;
    if (ty >= *nt1) return;
    const int e = t1e[ty];
    const int m0 = t1m[ty];
    const int Me = counts[e];
    const int rows = min(256, Me - m0);
    const int slot0 = offsets[e] + m0;
    const int n0 = blockIdx.x * 64;
    const int kz = blockIdx.z;
    float* yout = y + (size_t)kz * YSTRIDE;
    const size_t kbase = (size_t)kz * KPER2;

    __shared__ __align__(16) __bf16 As[256 * 64];   // 32 KB
    __shared__ __align__(16) float  Bs[64 * 64];    // 16 KB

    const int tid = threadIdx.x;
    const int lane = tid & 63;
    const int wv = tid >> 6;
    const int ln4 = lane >> 4;
    const int lr = lane & 15;
    const int wm = (wv >> 1) * 128;   // wave tile 128x32
    const int wn = (wv & 1) * 32;

    f32x4 acc[8][2];
#pragma unroll
    for (int i = 0; i < 8; ++i)
#pragma unroll
        for (int j = 0; j < 2; ++j) acc[i][j] = (f32x4){0.f, 0.f, 0.f, 0.f};

    // A: 2048 chunks (256 rows x 8); 8/thread; pre-swizzle (c&7)^(r&7)
    const char* asrc[8];
#pragma unroll
    for (int i = 0; i < 8; ++i) {
        int c = i * 256 + tid;
        int r = c >> 3;
        int rr = (r < rows) ? r : 0;
        int sj = (c & 7) ^ (r & 7);
        asrc[i] = (const char*)(act + (size_t)(slot0 + rr) * FDIM + kbase) + sj * 16;
    }
    // B: 1024 chunks (64 rows x 16); 4/thread; pre-swizzle (c&15)^(r&15)
    const char* bsrc[4];
#pragma unroll
    for (int i = 0; i < 4; ++i) {
        int c = i * 256 + tid;
        int r = c >> 4;
        int sj = (c & 15) ^ (r & 15);
        bsrc[i] = (const char*)(w2g + ((size_t)e * HDIM + n0 + r) * FDIM + kbase) + sj * 16;
    }

#define DMA_ALL2(K0) do { \
    _Pragma("unroll") \
    for (int i = 0; i < 8; ++i) \
        DMA16(asrc[i] + (size_t)(K0) * 128, (char*)As + (i * 256 + wv * 64) * 16); \
    _Pragma("unroll") \
    for (int i = 0; i < 4; ++i) \
        DMA16(bsrc[i] + (size_t)(K0) * 256, (char*)Bs + (i * 256 + wv * 64) * 16); \
    } while (0)

    int abase[8], axor[8];
#pragma unroll
    for (int i = 0; i < 8; ++i) {
        int row = wm + i * 16 + lr;
        abase[i] = row * 128;
        axor[i] = (row & 7) << 4;
    }
    int bbase[2], bxor[2];
#pragma unroll
    for (int i = 0; i < 2; ++i) {
        int row = wn + i * 16 + lr;
        bbase[i] = row * 256;
        bxor[i] = (row & 15) << 4;
    }

#define CMP2() do { \
    _Pragma("unroll") \
    for (int ksub = 0; ksub < 2; ++ksub) { \
        v8bf bf[2]; \
        _Pragma("unroll") \
        for (int ni = 0; ni < 2; ++ni) { \
            int in0 = ksub * 128 + ln4 * 32; \
            bf[ni] = pack8(*(const f32x4*)((const char*)Bs + bbase[ni] + ((in0) ^ bxor[ni])), \
                           *(const f32x4*)((const char*)Bs + bbase[ni] + ((in0 + 16) ^ bxor[ni]))); } \
        _Pragma("unroll") \
        for (int mi = 0; mi < 8; ++mi) { \
            v8bf af = *(const v8bf*)((const char*)As + abase[mi] + ((ksub * 64 + ln4 * 16) ^ axor[mi])); \
            _Pragma("unroll") \
            for (int ni = 0; ni < 2; ++ni) \
                acc[mi][ni] = __builtin_amdgcn_mfma_f32_16x16x32_bf16(af, bf[ni], acc[mi][ni], 0, 0, 0); \
        } } } while (0)

    DMA_ALL2(0);
    for (int ks = 0; ks < KPER2 / 64; ++ks) {
        WAITVM0();
        BARRIER();
        CMP2();
        WAITLGKM0();
        BARRIER();
        if (ks + 1 < KPER2 / 64) DMA_ALL2(ks + 1);
    }
#undef DMA_ALL2
#undef CMP2

    const int rj = ln4 * 4;
#pragma unroll
    for (int mi = 0; mi < 8; ++mi) {
#pragma unroll
        for (int j = 0; j < 4; ++j) {
            int rm = wm + mi * 16 + rj + j;
            if (rm < rows) {
                size_t rowoff = (size_t)(slot0 + rm) * HDIM + n0 + wn;
#pragma unroll
                for (int ni = 0; ni < 2; ++ni)
                    yout[rowoff + ni * 16 + lr] = acc[mi][ni][j];
            }
        }
    }
}

// ---------------- combine: out[t] = sum_kz( w0*y[s0] + w1*y[s1] ) ----------------
__global__ __launch_bounds__(256) void moe_combine(
    const float* __restrict__ y, const int* __restrict__ slot_of,
    const float* __restrict__ pair_wt, float* __restrict__ out)
{
    const int t = blockIdx.x;
    const int tid = threadIdx.x;
    const int s0 = slot_of[2 * t];
    const int s1 = slot_of[2 * t + 1];
    const float w0 = pair_wt[s0];
    const float w1 = pair_wt[s1];
    float4 a = {0.f, 0.f, 0.f, 0.f}, b = {0.f, 0.f, 0.f, 0.f};
#pragma unroll
    for (int k = 0; k < KSPLIT2; ++k) {
        const float4 ak = *(const float4*)(y + k * YSTRIDE + (size_t)s0 * HDIM + tid * 4);
        const float4 bk = *(const float4*)(y + k * YSTRIDE + (size_t)s1 * HDIM + tid * 4);
        a.x += ak.x; a.y += ak.y; a.z += ak.z; a.w += ak.w;
        b.x += bk.x; b.y += bk.y; b.z += bk.z; b.w += bk.w;
    }
    float4 o;
    o.x = w0 * a.x + w1 * b.x;
    o.y = w0 * a.y + w1 * b.y;
    o.z = w0 * a.z + w1 * b.z;
    o.w = w0 * a.w + w1 * b.w;
    *(float4*)(out + (size_t)t * HDIM + tid * 4) = o;
}

extern "C" void kernel_launch(void* const* d_in, const int* in_sizes, int n_in,
                              void* d_out, int out_size, void* d_ws, size_t ws_size,
                              hipStream_t stream) {
    const float* x   = (const float*)d_in[0];
    const float* gw  = (const float*)d_in[1];
    const float* w1  = (const float*)d_in[2];
    const float* w2  = (const float*)d_in[3];
    const float* w3  = (const float*)d_in[4];

    float* out    = (float*)d_out;
    float* logits = out + (size_t)NTOK * HDIM;

    char* ws = (char*)d_ws;
    int*    counts     = (int*)(ws + OFF_COUNTS);
    int*    offsets    = (int*)(ws + OFF_OFFSETS);
    int*    nt1        = (int*)(ws + OFF_NT1);
    int*    t1e        = (int*)(ws + OFF_T1E);
    int*    t1m        = (int*)(ws + OFF_T1M);
    int*    tok_idx    = (int*)(ws + OFF_TOKIDX);
    float*  tok_wt     = (float*)(ws + OFF_TOKWT);
    int*    pair_token = (int*)(ws + OFF_PAIRTOK);
    float*  pair_wt    = (float*)(ws + OFF_PAIRWT);
    int*    slot_of    = (int*)(ws + OFF_SLOTOF);
    __bf16* xb         = (__bf16*)(ws + OFF_XB);
    __bf16* act        = (__bf16*)(ws + OFF_ACT);
    float*  yb         = (float*)(ws + OFF_Y);

    hipMemsetAsync(counts, 0, 64, stream);

    moe_cvtx<<<dim3(NTOK * HDIM / 1024), dim3(256), 0, stream>>>(x, xb);
    moe_router<<<dim3(NTOK / 4), dim3(256), 0, stream>>>(x, gw, logits, counts, tok_idx, tok_wt);
    moe_scatter<<<dim3(1), dim3(256), 0, stream>>>(counts, tok_idx, tok_wt, offsets,
                                                   pair_token, pair_wt, slot_of,
                                                   t1e, t1m, nt1);
    moe_gemm1<<<dim3(FDIM / 32, MAXT), dim3(256), 0, stream>>>(
        xb, w1, w3, counts, offsets, pair_token, t1e, t1m, nt1, act);
    moe_gemm2<<<dim3(HDIM / 64, MAXT, KSPLIT2), dim3(256), 0, stream>>>(
        act, w2, counts, offsets, t1e, t1m, nt1, yb);
    moe_combine<<<dim3(NTOK), dim3(256), 0, stream>>>(yb, slot_of, pair_wt, out);
}